// Round 6
// baseline (497.330 us; speedup 1.0000x reference)
//
#include <hip/hip_runtime.h>
#include <math.h>

typedef __attribute__((ext_vector_type(4))) float f32x4;
typedef __attribute__((ext_vector_type(8))) short short8;
typedef unsigned int u32;

#define B_DIM 8192
#define N_FEAT 2048
#define K_ROWS 4096
#define INV_T 2.0f
#define EPSF 1e-12f

// gram tiling: 96x96 tiles over a 43x43 grid (upper triangle incl. diagonal)
#define GT 96
#define GGRID 43            // ceil(4096/96)
#define NTILES 946          // 43*44/2

// workspace layout (bytes)
#define FT_OFF    0ull
#define NORM2_OFF 67108864ull                 // fT = 4096*8192*2 bytes
#define INV_OFF   (NORM2_OFF + 16384)
#define RSUM_OFF  (INV_OFF + 32768)
#define PDOT_OFF  (RSUM_OFF + 16384)
#define ENT_OFF   (PDOT_OFF + 8192)           // 256 doubles of entropy partials
#define WS_END    (ENT_OFF + 2048)

__device__ __forceinline__ unsigned short f2bf(float x) {
  u32 u = __float_as_uint(x);
  u32 r = (u + 0x7fffu + ((u >> 16) & 1u)) >> 16;  // RNE, inputs are finite
  return (unsigned short)r;
}

__device__ __forceinline__ void gload16(const void* g, void* l) {
  __builtin_amdgcn_global_load_lds((const __attribute__((address_space(1))) u32*)g,
                                   (__attribute__((address_space(3))) u32*)l, 16, 0, 0);
}

// ---------------------------------------------------------------------------
// K_B: pure streaming stats. Thread-per-column, coalesced 1KB/wave row loads,
// no LDS, no __syncthreads.
//  norm2[k] = sum_b f[k,b]^2 (fp32 atomics), posdot[k] = sum_b f1*f2,
//  entropy in BITS (log2): neloss == mean(ent_bits), no ln2 factor needed.
// ---------------------------------------------------------------------------
__global__ __launch_bounds__(256) void stats_kernel(
    const float* __restrict__ f1, const float* __restrict__ f2,
    float* __restrict__ norm2, float* __restrict__ posdot,
    double* __restrict__ entpart) {
  const int col = blockIdx.x * 256 + threadIdx.x;
  const size_t base = (size_t)blockIdx.y * 64 * N_FEAT + col;
  const float* p1 = f1 + base;
  const float* p2 = f2 + base;
  float n1 = 0.f, n2 = 0.f, pd = 0.f, e0 = 0.f, e1 = 0.f;
#pragma unroll 8
  for (int r = 0; r < 64; ++r) {
    const float x = p1[(size_t)r * N_FEAT];
    const float y = p2[(size_t)r * N_FEAT];
    n1 += x * x; n2 += y * y; pd += x * y;
    e0 -= x * __log2f(x + EPSF) + (1.f - x) * __log2f(1.f - x + EPSF);
    e1 -= y * __log2f(y + EPSF) + (1.f - y) * __log2f(1.f - y + EPSF);
  }
  atomicAdd(&norm2[col], n1);
  atomicAdd(&norm2[N_FEAT + col], n2);
  atomicAdd(&posdot[col], pd);
  float ent = e0 + e1;
#pragma unroll
  for (int off = 1; off < 64; off <<= 1) ent += __shfl_xor(ent, off);
  if ((threadIdx.x & 63) == 0)
    atomicAdd(&entpart[(blockIdx.y * 8 + blockIdx.x + (threadIdx.x >> 6) * 64) & 255],
              (double)ent);
}

// ---------------------------------------------------------------------------
// K_A: transpose-only. 64(b) x 64(k) tile of f1 AND f2 -> bf16 fT rows.
// Write phase: 8 lanes x 8 elems per feature row -> every store instruction
// covers 8 rows x 128B fully-dense (round-4 WRITE_SIZE showed 2x write
// amplification from the old 16B-per-32B strided pattern).
// ---------------------------------------------------------------------------
__global__ __launch_bounds__(256) void transpose_kernel(
    const float* __restrict__ f1, const float* __restrict__ f2,
    unsigned short* __restrict__ fT) {
  __shared__ float T1[64][65];
  __shared__ float T2[64][65];
  const int b0 = blockIdx.x * 64, k0 = blockIdx.y * 64;
  const int t = threadIdx.x;
  const int kq = t & 15, br = t >> 4;
#pragma unroll
  for (int rr = 0; rr < 4; ++rr) {
    const int b = br + rr * 16;
    const f32x4 v1 = *(const f32x4*)&f1[(size_t)(b0 + b) * N_FEAT + k0 + kq * 4];
    const f32x4 v2 = *(const f32x4*)&f2[(size_t)(b0 + b) * N_FEAT + k0 + kq * 4];
#pragma unroll
    for (int c = 0; c < 4; ++c) { T1[b][kq * 4 + c] = v1[c]; T2[b][kq * 4 + c] = v2[c]; }
  }
  __syncthreads();
  const int kl0 = t >> 3;          // 0..31: feature row within tile
  const int b8 = (t & 7) * 8;      // 0..56: 8-elem batch chunk
#pragma unroll
  for (int rr = 0; rr < 2; ++rr) {
    const int kl = rr * 32 + kl0;
    short8 o;
#pragma unroll
    for (int j = 0; j < 8; ++j) o[j] = (short)f2bf(T1[b8 + j][kl]);
    *(short8*)&fT[(size_t)(k0 + kl) * B_DIM + b0 + b8] = o;
#pragma unroll
    for (int j = 0; j < 8; ++j) o[j] = (short)f2bf(T2[b8 + j][kl]);
    *(short8*)&fT[(size_t)(N_FEAT + k0 + kl) * B_DIM + b0 + b8] = o;
  }
}

// K1b: inv[i] = 1 / max(||row i||, eps)
__global__ void inv_kernel(const float* __restrict__ norm2, float* __restrict__ inv) {
  const int i = blockIdx.x * 256 + threadIdx.x;
  if (i < K_ROWS) inv[i] = 1.f / fmaxf(sqrtf(norm2[i]), EPSF);
}

// ---------------------------------------------------------------------------
// K2: symmetric Gram tiles (ti <= tj), 96x96 tile, BK=64, 4 waves (2x2, each
// 48x48 = 3x3 fragments), mfma_f32_16x16x32_bf16.
// 2-PHASE PREFETCH (T3-min recipe): double-buffered LDS; STAGE(kt+1) issued
// BEFORE compute(kt); single vmcnt(0)+barrier per K-step. Loads get a full
// compute-phase to land -> latency off the critical path (round-5 counters:
// MfmaUtil 24.8 / VALU 11.6 / HBM 27% -> ~64% stall, 1-phase serialization).
// Diagonal tiles zero their row==col element post-exp -> rowsum excludes diag.
// Ragged edge: staging rows clamped per-lane on the GLOBAL address (LDS dest
// stays linear), invalid entries zeroed post-exp, atomics guarded.
// ---------------------------------------------------------------------------
__global__ __launch_bounds__(256, 4) void gram_kernel(
    const unsigned short* __restrict__ fT, const float* __restrict__ inv,
    float* __restrict__ rowsum) {
  __shared__ __align__(16) unsigned short Al[2][GT * 64];
  __shared__ __align__(16) unsigned short Bl[2][GT * 64];
  // bijective XCD swizzle (m204): nwg=946, q=118, r=2
  const int orig = blockIdx.x;
  const int xcd = orig & 7;
  const int bid = (xcd < 2 ? xcd * 119 : 238 + (xcd - 2) * 118) + (orig >> 3);
  // triangular decode: bid -> (ti <= tj)
  int r = (int)((sqrtf(8.f * (float)bid + 1.f) - 1.f) * 0.5f);
  while ((r + 1) * (r + 2) / 2 <= bid) ++r;
  while (r * (r + 1) / 2 > bid) --r;
  const int tj = r, ti = bid - r * (r + 1) / 2;

  const int t = threadIdx.x, lane = t & 63, wave = t >> 6;
  const int wr = wave >> 1, wc = wave & 1;
  const int Rb = wr * 48, Cb = wc * 48;
  const int rowl = lane & 15, lhi = lane >> 4;
  const int srow8 = wave * 8 + (lane >> 3);  // staging row within 32-row group
  const int scol = (lane & 7) * 8;           // staging col (elements)
  const int tb = ti * GT, tjb = tj * GT;
  const bool diagT = (ti == tj);

  // per-lane staging source pointers, row clamped to 4095 (ragged edge)
  const unsigned short* pa[3];
  const unsigned short* pb[3];
#pragma unroll
  for (int it = 0; it < 3; ++it) {
    int ra = tb + it * 32 + srow8;  ra = ra < K_ROWS - 1 ? ra : K_ROWS - 1;
    int rb2 = tjb + it * 32 + srow8; rb2 = rb2 < K_ROWS - 1 ? rb2 : K_ROWS - 1;
    pa[it] = fT + (size_t)ra * B_DIM + scol;
    pb[it] = fT + (size_t)rb2 * B_DIM + scol;
  }

  f32x4 acc[3][3];
  const f32x4 zero = {0.f, 0.f, 0.f, 0.f};
#pragma unroll
  for (int m = 0; m < 3; ++m)
#pragma unroll
    for (int n = 0; n < 3; ++n) acc[m][n] = zero;

#define STAGE(buf, kt)                                                        \
  do {                                                                        \
    const size_t ko_ = (size_t)(kt) * 64;                                     \
    _Pragma("unroll")                                                         \
    for (int it = 0; it < 3; ++it) {                                          \
      gload16(pa[it] + ko_, &Al[buf][(it * 32 + wave * 8) * 64]);             \
      gload16(pb[it] + ko_, &Bl[buf][(it * 32 + wave * 8) * 64]);             \
    }                                                                         \
  } while (0)

#define COMPUTE(buf)                                                          \
  do {                                                                        \
    _Pragma("unroll")                                                         \
    for (int kk = 0; kk < 64; kk += 32) {                                     \
      short8 af[3], bfv[3];                                                   \
      const int kc = kk + lhi * 8;                                            \
      _Pragma("unroll")                                                       \
      for (int m = 0; m < 3; ++m)                                             \
        af[m] = *(const short8*)&Al[buf][(Rb + m * 16 + rowl) * 64 + kc];     \
      _Pragma("unroll")                                                       \
      for (int n = 0; n < 3; ++n)                                             \
        bfv[n] = *(const short8*)&Bl[buf][(Cb + n * 16 + rowl) * 64 + kc];    \
      _Pragma("unroll")                                                       \
      for (int m = 0; m < 3; ++m)                                             \
        _Pragma("unroll")                                                     \
        for (int n = 0; n < 3; ++n)                                           \
          acc[m][n] =                                                         \
              __builtin_amdgcn_mfma_f32_16x16x32_bf16(af[m], bfv[n],          \
                                                      acc[m][n], 0, 0, 0);    \
    }                                                                         \
  } while (0)

  // prologue: stage K-step 0 into buffer 0
  STAGE(0, 0);
  asm volatile("s_waitcnt vmcnt(0)" ::: "memory");
  __syncthreads();
#pragma unroll 2
  for (int kt = 0; kt < B_DIM / 64 - 1; ++kt) {
    const int cur = kt & 1;
    STAGE(cur ^ 1, kt + 1);   // issue next-tile loads first (overlap compute)
    COMPUTE(cur);
    asm volatile("s_waitcnt vmcnt(0)" ::: "memory");
    __syncthreads();
  }
  COMPUTE((B_DIM / 64 - 1) & 1);  // last K-step, no prefetch

#undef STAGE
#undef COMPUTE

  // epilogue: scale, exp, zero invalid (ragged) + main-diagonal entries,
  // then row + col sums
  float invj[3];
  bool cval[3];
#pragma unroll
  for (int n = 0; n < 3; ++n) {
    const int cg = tjb + Cb + n * 16 + rowl;
    cval[n] = cg < K_ROWS;
    invj[n] = inv[cg < K_ROWS ? cg : K_ROWS - 1];
  }
#pragma unroll
  for (int m = 0; m < 3; ++m) {
#pragma unroll
    for (int rg = 0; rg < 4; ++rg) {
      const int rloc = Rb + m * 16 + lhi * 4 + rg;  // row within tile
      const int rgl = tb + rloc;
      const bool rv = rgl < K_ROWS;
      const float invi = inv[rv ? rgl : K_ROWS - 1];
#pragma unroll
      for (int n = 0; n < 3; ++n) {
        const int cloc = Cb + n * 16 + rowl;        // col within tile
        const float e = __expf(acc[m][n][rg] * invi * invj[n] * INV_T);
        const bool keep = rv && cval[n] && !(diagT && rloc == cloc);
        acc[m][n][rg] = keep ? e : 0.f;
      }
    }
  }
  // row-side sums (rows of ti)
#pragma unroll
  for (int m = 0; m < 3; ++m) {
#pragma unroll
    for (int rg = 0; rg < 4; ++rg) {
      float s = acc[m][0][rg] + acc[m][1][rg] + acc[m][2][rg];
      s += __shfl_xor(s, 1); s += __shfl_xor(s, 2);
      s += __shfl_xor(s, 4); s += __shfl_xor(s, 8);
      if (rowl == 0) {
        const int rgl = tb + Rb + m * 16 + lhi * 4 + rg;
        if (rgl < K_ROWS) atomicAdd(&rowsum[rgl], s);
      }
    }
  }
  // col-side sums (rows of tj) for off-diagonal tiles
  if (!diagT) {
#pragma unroll
    for (int n = 0; n < 3; ++n) {
      float s = 0.f;
#pragma unroll
      for (int m = 0; m < 3; ++m)
#pragma unroll
        for (int rg = 0; rg < 4; ++rg) s += acc[m][n][rg];
      s += __shfl_xor(s, 16); s += __shfl_xor(s, 32);
      if (lhi == 0) {
        const int cg = tjb + Cb + n * 16 + rowl;
        if (cg < K_ROWS) atomicAdd(&rowsum[cg], s);
      }
    }
  }
}

// ---------------------------------------------------------------------------
// K3: lse_i = log(rowsum_i)  (diag excluded in gram), pos_i exact fp32;
// neloss = mean of entropy-in-bits. Final scalar.
// ---------------------------------------------------------------------------
__global__ __launch_bounds__(256) void final_kernel(
    const float* __restrict__ rowsum,
    const float* __restrict__ inv, const float* __restrict__ posdot,
    const double* __restrict__ entpart, float* __restrict__ out) {
  __shared__ double red[4];
  __shared__ double rede[4];
  const int t = threadIdx.x, lane = t & 63, wave = t >> 6;
  double ssum = 0.0;
  for (int i = t; i < K_ROWS; i += 256) {
    const float invi = inv[i];
    const float lse = __logf(rowsum[i]);
    const int ip = (i < N_FEAT) ? i : i - N_FEAT;
    const int io = (i < N_FEAT) ? i + N_FEAT : i - N_FEAT;
    const float pos = posdot[ip] * invi * inv[io] * INV_T;
    ssum += (double)(lse - pos);
  }
  double esum = entpart[t];
#pragma unroll
  for (int off = 1; off < 64; off <<= 1) {
    ssum += __shfl_xor(ssum, off);
    esum += __shfl_xor(esum, off);
  }
  if (lane == 0) { red[wave] = ssum; rede[wave] = esum; }
  __syncthreads();
  if (t == 0) {
    const double ce = (red[0] + red[1] + red[2] + red[3]) / (double)K_ROWS;
    const double etot = rede[0] + rede[1] + rede[2] + rede[3];
    const double nel = etot / ((double)K_ROWS * (double)B_DIM);  // already bits
    out[0] = (float)(ce - nel);
  }
}

extern "C" void kernel_launch(void* const* d_in, const int* in_sizes, int n_in,
                              void* d_out, int out_size, void* d_ws, size_t ws_size,
                              hipStream_t stream) {
  const float* f1 = (const float*)d_in[0];
  const float* f2 = (const float*)d_in[1];
  char* ws = (char*)d_ws;
  unsigned short* fT = (unsigned short*)(ws + FT_OFF);
  float* norm2 = (float*)(ws + NORM2_OFF);
  float* inv = (float*)(ws + INV_OFF);
  float* rowsum = (float*)(ws + RSUM_OFF);
  float* posdot = (float*)(ws + PDOT_OFF);
  double* entpart = (double*)(ws + ENT_OFF);

  // zero all accumulators (ws is poisoned 0xAA before every call)
  hipMemsetAsync(ws + NORM2_OFF, 0, (size_t)(WS_END - NORM2_OFF), stream);

  stats_kernel<<<dim3(N_FEAT / 256, 128), 256, 0, stream>>>(f1, f2, norm2, posdot, entpart);
  inv_kernel<<<K_ROWS / 256, 256, 0, stream>>>(norm2, inv);
  transpose_kernel<<<dim3(B_DIM / 64, N_FEAT / 64), 256, 0, stream>>>(f1, f2, fT);
  gram_kernel<<<NTILES, 256, 0, stream>>>(fT, inv, rowsum);
  final_kernel<<<1, 256, 0, stream>>>(rowsum, inv, posdot, entpart, (float*)d_out);
}

// Round 7
// 329.391 us; speedup vs baseline: 1.5098x; 1.5098x over previous
//
#include <hip/hip_runtime.h>
#include <math.h>

typedef __attribute__((ext_vector_type(4))) float f32x4;
typedef __attribute__((ext_vector_type(8))) short short8;
typedef unsigned int u32;

#define B_DIM 8192
#define N_FEAT 2048
#define K_ROWS 4096
#define INV_T 2.0f
#define EPSF 1e-12f

// gram tiling: 96x96 tiles over a 43x43 grid (upper triangle incl. diagonal)
#define GT 96
#define GGRID 43            // ceil(4096/96)
#define NTILES 946          // 43*44/2

// workspace layout (bytes)
#define FT_OFF    0ull
#define NORM2_OFF 67108864ull                 // fT = 4096*8192*2 bytes
#define INV_OFF   (NORM2_OFF + 16384)
#define RSUM_OFF  (INV_OFF + 32768)
#define PDOT_OFF  (RSUM_OFF + 16384)
#define ENT_OFF   (PDOT_OFF + 8192)           // 256 doubles of entropy partials
#define WS_END    (ENT_OFF + 2048)

__device__ __forceinline__ unsigned short f2bf(float x) {
  u32 u = __float_as_uint(x);
  u32 r = (u + 0x7fffu + ((u >> 16) & 1u)) >> 16;  // RNE, inputs are finite
  return (unsigned short)r;
}

__device__ __forceinline__ void gload16(const void* g, void* l) {
  __builtin_amdgcn_global_load_lds((const __attribute__((address_space(1))) u32*)g,
                                   (__attribute__((address_space(3))) u32*)l, 16, 0, 0);
}

// ---------------------------------------------------------------------------
// K_B: pure streaming stats. Thread-per-column, coalesced 1KB/wave row loads,
// no LDS, no __syncthreads.
//  norm2[k] = sum_b f[k,b]^2 (fp32 atomics), posdot[k] = sum_b f1*f2,
//  entropy in BITS (log2): neloss == mean(ent_bits), no ln2 factor needed.
// ---------------------------------------------------------------------------
__global__ __launch_bounds__(256) void stats_kernel(
    const float* __restrict__ f1, const float* __restrict__ f2,
    float* __restrict__ norm2, float* __restrict__ posdot,
    double* __restrict__ entpart) {
  const int col = blockIdx.x * 256 + threadIdx.x;
  const size_t base = (size_t)blockIdx.y * 64 * N_FEAT + col;
  const float* p1 = f1 + base;
  const float* p2 = f2 + base;
  float n1 = 0.f, n2 = 0.f, pd = 0.f, e0 = 0.f, e1 = 0.f;
#pragma unroll 8
  for (int r = 0; r < 64; ++r) {
    const float x = p1[(size_t)r * N_FEAT];
    const float y = p2[(size_t)r * N_FEAT];
    n1 += x * x; n2 += y * y; pd += x * y;
    e0 -= x * __log2f(x + EPSF) + (1.f - x) * __log2f(1.f - x + EPSF);
    e1 -= y * __log2f(y + EPSF) + (1.f - y) * __log2f(1.f - y + EPSF);
  }
  atomicAdd(&norm2[col], n1);
  atomicAdd(&norm2[N_FEAT + col], n2);
  atomicAdd(&posdot[col], pd);
  float ent = e0 + e1;
#pragma unroll
  for (int off = 1; off < 64; off <<= 1) ent += __shfl_xor(ent, off);
  if ((threadIdx.x & 63) == 0)
    atomicAdd(&entpart[(blockIdx.y * 8 + blockIdx.x + (threadIdx.x >> 6) * 64) & 255],
              (double)ent);
}

// ---------------------------------------------------------------------------
// K_A: transpose-only. 64(b) x 64(k) tile of f1 AND f2 -> bf16 fT rows.
// Write phase: 8 lanes x 8 elems per feature row -> dense 128B segments.
// ---------------------------------------------------------------------------
__global__ __launch_bounds__(256) void transpose_kernel(
    const float* __restrict__ f1, const float* __restrict__ f2,
    unsigned short* __restrict__ fT) {
  __shared__ float T1[64][65];
  __shared__ float T2[64][65];
  const int b0 = blockIdx.x * 64, k0 = blockIdx.y * 64;
  const int t = threadIdx.x;
  const int kq = t & 15, br = t >> 4;
#pragma unroll
  for (int rr = 0; rr < 4; ++rr) {
    const int b = br + rr * 16;
    const f32x4 v1 = *(const f32x4*)&f1[(size_t)(b0 + b) * N_FEAT + k0 + kq * 4];
    const f32x4 v2 = *(const f32x4*)&f2[(size_t)(b0 + b) * N_FEAT + k0 + kq * 4];
#pragma unroll
    for (int c = 0; c < 4; ++c) { T1[b][kq * 4 + c] = v1[c]; T2[b][kq * 4 + c] = v2[c]; }
  }
  __syncthreads();
  const int kl0 = t >> 3;          // 0..31: feature row within tile
  const int b8 = (t & 7) * 8;      // 0..56: 8-elem batch chunk
#pragma unroll
  for (int rr = 0; rr < 2; ++rr) {
    const int kl = rr * 32 + kl0;
    short8 o;
#pragma unroll
    for (int j = 0; j < 8; ++j) o[j] = (short)f2bf(T1[b8 + j][kl]);
    *(short8*)&fT[(size_t)(k0 + kl) * B_DIM + b0 + b8] = o;
#pragma unroll
    for (int j = 0; j < 8; ++j) o[j] = (short)f2bf(T2[b8 + j][kl]);
    *(short8*)&fT[(size_t)(N_FEAT + k0 + kl) * B_DIM + b0 + b8] = o;
  }
}

// K1b: inv[i] = 1 / max(||row i||, eps)
__global__ void inv_kernel(const float* __restrict__ norm2, float* __restrict__ inv) {
  const int i = blockIdx.x * 256 + threadIdx.x;
  if (i < K_ROWS) inv[i] = 1.f / fmaxf(sqrtf(norm2[i]), EPSF);
}

// ---------------------------------------------------------------------------
// K2: symmetric Gram tiles (ti <= tj), 96x96, BK=64, 4 waves (2x2 of 48x48),
// mfma_f32_16x16x32_bf16. SINGLE-buffer LDS (round-5 dbuf regressed via
// occupancy loss; reverted). BANK-CONFLICT XOR SWIZZLE (rule #21): LDS 16B
// slot s of row r holds global slot s^(r&7) -- achieved by permuting the
// per-lane GLOBAL source col (same 128B line, coalescing intact, LDS dest
// linear as gload_lds requires); ds_read applies the same XOR. Kills the
// 16-way conflict (round-4 PMC: 7e7 conflict-cycles = 47% of kernel).
// Diagonal tiles zero their row==col element post-exp.
// Ragged edge: staging rows clamped per-lane on the GLOBAL address,
// invalid entries zeroed post-exp, atomics guarded.
// ---------------------------------------------------------------------------
__global__ __launch_bounds__(256, 4) void gram_kernel(
    const unsigned short* __restrict__ fT, const float* __restrict__ inv,
    float* __restrict__ rowsum) {
  __shared__ __align__(16) unsigned short Al[GT * 64];
  __shared__ __align__(16) unsigned short Bl[GT * 64];
  // bijective XCD swizzle (m204): nwg=946, q=118, r=2
  const int orig = blockIdx.x;
  const int xcd = orig & 7;
  const int bid = (xcd < 2 ? xcd * 119 : 238 + (xcd - 2) * 118) + (orig >> 3);
  // triangular decode: bid -> (ti <= tj)
  int r = (int)((sqrtf(8.f * (float)bid + 1.f) - 1.f) * 0.5f);
  while ((r + 1) * (r + 2) / 2 <= bid) ++r;
  while (r * (r + 1) / 2 > bid) --r;
  const int tj = r, ti = bid - r * (r + 1) / 2;

  const int t = threadIdx.x, lane = t & 63, wave = t >> 6;
  const int wr = wave >> 1, wc = wave & 1;
  const int Rb = wr * 48, Cb = wc * 48;
  const int rowl = lane & 15, lhi = lane >> 4;
  const int srow8 = wave * 8 + (lane >> 3);  // staging row within 32-row group
  // pre-swizzled global col: slot (lane&7) of LDS row gets global slot
  // (lane&7)^(lane>>3); row parity (r&7)==(lane>>3) since bases are 8-aligned
  const int scol = (((lane & 7) ^ (lane >> 3)) * 8);
  const int tb = ti * GT, tjb = tj * GT;
  const bool diagT = (ti == tj);

  // per-lane staging source pointers, row clamped to 4095 (ragged edge)
  const unsigned short* pa[3];
  const unsigned short* pb[3];
#pragma unroll
  for (int it = 0; it < 3; ++it) {
    int ra = tb + it * 32 + srow8;  ra = ra < K_ROWS - 1 ? ra : K_ROWS - 1;
    int rb2 = tjb + it * 32 + srow8; rb2 = rb2 < K_ROWS - 1 ? rb2 : K_ROWS - 1;
    pa[it] = fT + (size_t)ra * B_DIM + scol;
    pb[it] = fT + (size_t)rb2 * B_DIM + scol;
  }

  f32x4 acc[3][3];
  const f32x4 zero = {0.f, 0.f, 0.f, 0.f};
#pragma unroll
  for (int m = 0; m < 3; ++m)
#pragma unroll
    for (int n = 0; n < 3; ++n) acc[m][n] = zero;

  for (int kt = 0; kt < B_DIM / 64; ++kt) {
    const size_t ko = (size_t)kt * 64;
#pragma unroll
    for (int it = 0; it < 3; ++it) {
      gload16(pa[it] + ko, &Al[(it * 32 + wave * 8) * 64]);
      gload16(pb[it] + ko, &Bl[(it * 32 + wave * 8) * 64]);
    }
    asm volatile("s_waitcnt vmcnt(0)" ::: "memory");
    __syncthreads();
#pragma unroll
    for (int kk = 0; kk < 64; kk += 32) {
      short8 af[3], bfv[3];
      const int sg = (kk >> 3) + lhi;          // logical 16B slot in row
      const int so = ((sg ^ (rowl & 7)) << 3); // swizzled element offset
#pragma unroll
      for (int m = 0; m < 3; ++m)
        af[m] = *(const short8*)&Al[(Rb + m * 16 + rowl) * 64 + so];
#pragma unroll
      for (int n = 0; n < 3; ++n)
        bfv[n] = *(const short8*)&Bl[(Cb + n * 16 + rowl) * 64 + so];
#pragma unroll
      for (int m = 0; m < 3; ++m)
#pragma unroll
        for (int n = 0; n < 3; ++n)
          acc[m][n] = __builtin_amdgcn_mfma_f32_16x16x32_bf16(af[m], bfv[n], acc[m][n], 0, 0, 0);
    }
    __syncthreads();
  }

  // epilogue: scale, exp, zero invalid (ragged) + main-diagonal entries,
  // then row + col sums
  float invj[3];
  bool cval[3];
#pragma unroll
  for (int n = 0; n < 3; ++n) {
    const int cg = tjb + Cb + n * 16 + rowl;
    cval[n] = cg < K_ROWS;
    invj[n] = inv[cg < K_ROWS ? cg : K_ROWS - 1];
  }
#pragma unroll
  for (int m = 0; m < 3; ++m) {
#pragma unroll
    for (int rg = 0; rg < 4; ++rg) {
      const int rloc = Rb + m * 16 + lhi * 4 + rg;  // row within tile
      const int rgl = tb + rloc;
      const bool rv = rgl < K_ROWS;
      const float invi = inv[rv ? rgl : K_ROWS - 1];
#pragma unroll
      for (int n = 0; n < 3; ++n) {
        const int cloc = Cb + n * 16 + rowl;        // col within tile
        const float e = __expf(acc[m][n][rg] * invi * invj[n] * INV_T);
        const bool keep = rv && cval[n] && !(diagT && rloc == cloc);
        acc[m][n][rg] = keep ? e : 0.f;
      }
    }
  }
  // row-side sums (rows of ti)
#pragma unroll
  for (int m = 0; m < 3; ++m) {
#pragma unroll
    for (int rg = 0; rg < 4; ++rg) {
      float s = acc[m][0][rg] + acc[m][1][rg] + acc[m][2][rg];
      s += __shfl_xor(s, 1); s += __shfl_xor(s, 2);
      s += __shfl_xor(s, 4); s += __shfl_xor(s, 8);
      if (rowl == 0) {
        const int rgl = tb + Rb + m * 16 + lhi * 4 + rg;
        if (rgl < K_ROWS) atomicAdd(&rowsum[rgl], s);
      }
    }
  }
  // col-side sums (rows of tj) for off-diagonal tiles
  if (!diagT) {
#pragma unroll
    for (int n = 0; n < 3; ++n) {
      float s = 0.f;
#pragma unroll
      for (int m = 0; m < 3; ++m)
#pragma unroll
        for (int rg = 0; rg < 4; ++rg) s += acc[m][n][rg];
      s += __shfl_xor(s, 16); s += __shfl_xor(s, 32);
      if (lhi == 0) {
        const int cg = tjb + Cb + n * 16 + rowl;
        if (cg < K_ROWS) atomicAdd(&rowsum[cg], s);
      }
    }
  }
}

// ---------------------------------------------------------------------------
// K3: lse_i = log(rowsum_i)  (diag excluded in gram), pos_i exact fp32;
// neloss = mean of entropy-in-bits. Final scalar.
// ---------------------------------------------------------------------------
__global__ __launch_bounds__(256) void final_kernel(
    const float* __restrict__ rowsum,
    const float* __restrict__ inv, const float* __restrict__ posdot,
    const double* __restrict__ entpart, float* __restrict__ out) {
  __shared__ double red[4];
  __shared__ double rede[4];
  const int t = threadIdx.x, lane = t & 63, wave = t >> 6;
  double ssum = 0.0;
  for (int i = t; i < K_ROWS; i += 256) {
    const float invi = inv[i];
    const float lse = __logf(rowsum[i]);
    const int ip = (i < N_FEAT) ? i : i - N_FEAT;
    const int io = (i < N_FEAT) ? i + N_FEAT : i - N_FEAT;
    const float pos = posdot[ip] * invi * inv[io] * INV_T;
    ssum += (double)(lse - pos);
  }
  double esum = entpart[t];
#pragma unroll
  for (int off = 1; off < 64; off <<= 1) {
    ssum += __shfl_xor(ssum, off);
    esum += __shfl_xor(esum, off);
  }
  if (lane == 0) { red[wave] = ssum; rede[wave] = esum; }
  __syncthreads();
  if (t == 0) {
    const double ce = (red[0] + red[1] + red[2] + red[3]) / (double)K_ROWS;
    const double etot = rede[0] + rede[1] + rede[2] + rede[3];
    const double nel = etot / ((double)K_ROWS * (double)B_DIM);  // already bits
    out[0] = (float)(ce - nel);
  }
}

extern "C" void kernel_launch(void* const* d_in, const int* in_sizes, int n_in,
                              void* d_out, int out_size, void* d_ws, size_t ws_size,
                              hipStream_t stream) {
  const float* f1 = (const float*)d_in[0];
  const float* f2 = (const float*)d_in[1];
  char* ws = (char*)d_ws;
  unsigned short* fT = (unsigned short*)(ws + FT_OFF);
  float* norm2 = (float*)(ws + NORM2_OFF);
  float* inv = (float*)(ws + INV_OFF);
  float* rowsum = (float*)(ws + RSUM_OFF);
  float* posdot = (float*)(ws + PDOT_OFF);
  double* entpart = (double*)(ws + ENT_OFF);

  // zero all accumulators (ws is poisoned 0xAA before every call)
  hipMemsetAsync(ws + NORM2_OFF, 0, (size_t)(WS_END - NORM2_OFF), stream);

  stats_kernel<<<dim3(N_FEAT / 256, 128), 256, 0, stream>>>(f1, f2, norm2, posdot, entpart);
  inv_kernel<<<K_ROWS / 256, 256, 0, stream>>>(norm2, inv);
  transpose_kernel<<<dim3(B_DIM / 64, N_FEAT / 64), 256, 0, stream>>>(f1, f2, fT);
  gram_kernel<<<NTILES, 256, 0, stream>>>(fT, inv, rowsum);
  final_kernel<<<1, 256, 0, stream>>>(rowsum, inv, posdot, entpart, (float*)d_out);
}

// Round 9
// 325.286 us; speedup vs baseline: 1.5289x; 1.0126x over previous
//
#include <hip/hip_runtime.h>
#include <math.h>

typedef __attribute__((ext_vector_type(4))) float f32x4;
typedef __attribute__((ext_vector_type(8))) short short8;
typedef unsigned int u32;

#define B_DIM 8192
#define N_FEAT 2048
#define K_ROWS 4096
#define INV_T 2.0f
#define EPSF 1e-12f

// gram tiling: 96x96 tiles over a 43x43 grid (upper triangle incl. diagonal)
#define GT 96
#define GGRID 43            // ceil(4096/96)
#define NTILES 946          // 43*44/2

// workspace layout (bytes)
#define FT_OFF    0ull
#define NORM2_OFF 67108864ull                 // fT = 4096*8192*2 bytes
#define RSUM_OFF  (NORM2_OFF + 16384)
#define PDOT_OFF  (RSUM_OFF + 16384)
#define ENT_OFF   (PDOT_OFF + 8192)           // 256 doubles of entropy partials
#define WS_END    (ENT_OFF + 2048)

__device__ __forceinline__ unsigned short f2bf(float x) {
  u32 u = __float_as_uint(x);
  u32 r = (u + 0x7fffu + ((u >> 16) & 1u)) >> 16;  // RNE, inputs are finite
  return (unsigned short)r;
}

__device__ __forceinline__ void gload16(const void* g, void* l) {
  __builtin_amdgcn_global_load_lds((const __attribute__((address_space(1))) u32*)g,
                                   (__attribute__((address_space(3))) u32*)l, 16, 0, 0);
}

// ---------------------------------------------------------------------------
// K1: FUSED prep = transpose + stats (single read pass of f1/f2).
// Load 64(b)x64(k) tiles of f1,f2 -> LDS fp32; write phase converts to bf16
// fT rows (dense 128B segments) AND accumulates per-feature stats from the
// same LDS-resident fp32 values (exact, matches reference math):
//   norm2[k] = sum_b f^2, posdot[k] = sum_b f1*f2, entropy in BITS (log2).
// Contention discipline (round-3 lesson): 8-lane shfl pre-reduce -> 196
// atomics/block total; entropy one double atomic per wave to 256 slots.
// ---------------------------------------------------------------------------
__global__ __launch_bounds__(256) void prep_kernel(
    const float* __restrict__ f1, const float* __restrict__ f2,
    unsigned short* __restrict__ fT, float* __restrict__ norm2,
    float* __restrict__ posdot, double* __restrict__ entpart) {
  __shared__ float T1[64][65];
  __shared__ float T2[64][65];
  const int b0 = blockIdx.x * 64, k0 = blockIdx.y * 64;
  const int t = threadIdx.x;
  const int kq = t & 15, br = t >> 4;
#pragma unroll
  for (int rr = 0; rr < 4; ++rr) {
    const int b = br + rr * 16;
    const f32x4 v1 = *(const f32x4*)&f1[(size_t)(b0 + b) * N_FEAT + k0 + kq * 4];
    const f32x4 v2 = *(const f32x4*)&f2[(size_t)(b0 + b) * N_FEAT + k0 + kq * 4];
#pragma unroll
    for (int c = 0; c < 4; ++c) { T1[b][kq * 4 + c] = v1[c]; T2[b][kq * 4 + c] = v2[c]; }
  }
  __syncthreads();
  const int kl0 = t >> 3;          // 0..31: feature row within tile
  const int b8 = (t & 7) * 8;      // 0..56: 8-elem batch chunk
  float ent = 0.f;
#pragma unroll
  for (int rr = 0; rr < 2; ++rr) {
    const int kl = rr * 32 + kl0;
    float n1 = 0.f, n2 = 0.f, pd = 0.f;
    short8 o1v, o2v;
#pragma unroll
    for (int j = 0; j < 8; ++j) {
      const float x = T1[b8 + j][kl];
      const float y = T2[b8 + j][kl];
      n1 += x * x; n2 += y * y; pd += x * y;
      ent -= x * __log2f(x + EPSF) + (1.f - x) * __log2f(1.f - x + EPSF);
      ent -= y * __log2f(y + EPSF) + (1.f - y) * __log2f(1.f - y + EPSF);
      o1v[j] = (short)f2bf(x);
      o2v[j] = (short)f2bf(y);
    }
    *(short8*)&fT[(size_t)(k0 + kl) * B_DIM + b0 + b8] = o1v;
    *(short8*)&fT[(size_t)(N_FEAT + k0 + kl) * B_DIM + b0 + b8] = o2v;
    // reduce across the 8 lanes sharing this feature row
    n1 += __shfl_xor(n1, 1); n1 += __shfl_xor(n1, 2); n1 += __shfl_xor(n1, 4);
    n2 += __shfl_xor(n2, 1); n2 += __shfl_xor(n2, 2); n2 += __shfl_xor(n2, 4);
    pd += __shfl_xor(pd, 1); pd += __shfl_xor(pd, 2); pd += __shfl_xor(pd, 4);
    if ((t & 7) == 0) {
      atomicAdd(&norm2[k0 + kl], n1);
      atomicAdd(&norm2[N_FEAT + k0 + kl], n2);
      atomicAdd(&posdot[k0 + kl], pd);
    }
  }
#pragma unroll
  for (int off = 1; off < 64; off <<= 1) ent += __shfl_xor(ent, off);
  if ((t & 63) == 0)
    atomicAdd(&entpart[(blockIdx.x * 37 + blockIdx.y * 5 + (t >> 6)) & 255],
              (double)ent);
}

// ---------------------------------------------------------------------------
// K2: symmetric Gram tiles (ti <= tj), 96x96, BK=64, 4 waves (2x2 of 48x48),
// mfma_f32_16x16x32_bf16. Single-buffer LDS; XOR bank-swizzle via pre-swizzled
// global source + matching ds_read XOR (round-6: conflicts 7e7 -> 0,
// gram 240 -> 164 us = 874 TF, exactly the m97-structure ceiling; frozen).
// inv folded in: invi = 1/max(sqrt(norm2),eps) computed in epilogue.
// Diagonal tiles zero their row==col element post-exp.
// Ragged edge: staging rows clamped per-lane on the GLOBAL address,
// invalid entries zeroed post-exp, atomics guarded.
// ---------------------------------------------------------------------------
__global__ __launch_bounds__(256, 4) void gram_kernel(
    const unsigned short* __restrict__ fT, const float* __restrict__ norm2,
    float* __restrict__ rowsum) {
  __shared__ __align__(16) unsigned short Al[GT * 64];
  __shared__ __align__(16) unsigned short Bl[GT * 64];
  // bijective XCD swizzle (m204): nwg=946, q=118, r=2
  const int orig = blockIdx.x;
  const int xcd = orig & 7;
  const int bid = (xcd < 2 ? xcd * 119 : 238 + (xcd - 2) * 118) + (orig >> 3);
  // triangular decode: bid -> (ti <= tj)
  int r = (int)((sqrtf(8.f * (float)bid + 1.f) - 1.f) * 0.5f);
  while ((r + 1) * (r + 2) / 2 <= bid) ++r;
  while (r * (r + 1) / 2 > bid) --r;
  const int tj = r, ti = bid - r * (r + 1) / 2;

  const int t = threadIdx.x, lane = t & 63, wave = t >> 6;
  const int wr = wave >> 1, wc = wave & 1;
  const int Rb = wr * 48, Cb = wc * 48;
  const int rowl = lane & 15, lhi = lane >> 4;
  const int srow8 = wave * 8 + (lane >> 3);  // staging row within 32-row group
  // pre-swizzled global col: slot (lane&7) of LDS row gets global slot
  // (lane&7)^(lane>>3); row parity (r&7)==(lane>>3) since bases are 8-aligned
  const int scol = (((lane & 7) ^ (lane >> 3)) * 8);
  const int tb = ti * GT, tjb = tj * GT;
  const bool diagT = (ti == tj);

  // per-lane staging source pointers, row clamped to 4095 (ragged edge)
  const unsigned short* pa[3];
  const unsigned short* pb[3];
#pragma unroll
  for (int it = 0; it < 3; ++it) {
    int ra = tb + it * 32 + srow8;  ra = ra < K_ROWS - 1 ? ra : K_ROWS - 1;
    int rb2 = tjb + it * 32 + srow8; rb2 = rb2 < K_ROWS - 1 ? rb2 : K_ROWS - 1;
    pa[it] = fT + (size_t)ra * B_DIM + scol;
    pb[it] = fT + (size_t)rb2 * B_DIM + scol;
  }

  f32x4 acc[3][3];
  const f32x4 zero = {0.f, 0.f, 0.f, 0.f};
#pragma unroll
  for (int m = 0; m < 3; ++m)
#pragma unroll
    for (int n = 0; n < 3; ++n) acc[m][n] = zero;

  for (int kt = 0; kt < B_DIM / 64; ++kt) {
    const size_t ko = (size_t)kt * 64;
#pragma unroll
    for (int it = 0; it < 3; ++it) {
      gload16(pa[it] + ko, &Al[(it * 32 + wave * 8) * 64]);
      gload16(pb[it] + ko, &Bl[(it * 32 + wave * 8) * 64]);
    }
    asm volatile("s_waitcnt vmcnt(0)" ::: "memory");
    __syncthreads();
#pragma unroll
    for (int kk = 0; kk < 64; kk += 32) {
      short8 af[3], bfv[3];
      const int sg = (kk >> 3) + lhi;          // logical 16B slot in row
      const int so = ((sg ^ (rowl & 7)) << 3); // swizzled element offset
#pragma unroll
      for (int m = 0; m < 3; ++m)
        af[m] = *(const short8*)&Al[(Rb + m * 16 + rowl) * 64 + so];
#pragma unroll
      for (int n = 0; n < 3; ++n)
        bfv[n] = *(const short8*)&Bl[(Cb + n * 16 + rowl) * 64 + so];
#pragma unroll
      for (int m = 0; m < 3; ++m)
#pragma unroll
        for (int n = 0; n < 3; ++n)
          acc[m][n] = __builtin_amdgcn_mfma_f32_16x16x32_bf16(af[m], bfv[n], acc[m][n], 0, 0, 0);
    }
    __syncthreads();
  }

  // epilogue: scale by 1/(|fi||fj|)/T, exp, zero invalid (ragged) +
  // main-diagonal entries, then row + col sums
  float invj[3];
  bool cval[3];
#pragma unroll
  for (int n = 0; n < 3; ++n) {
    const int cg = tjb + Cb + n * 16 + rowl;
    cval[n] = cg < K_ROWS;
    invj[n] = 1.f / fmaxf(sqrtf(norm2[cg < K_ROWS ? cg : K_ROWS - 1]), EPSF);
  }
#pragma unroll
  for (int m = 0; m < 3; ++m) {
#pragma unroll
    for (int rg = 0; rg < 4; ++rg) {
      const int rloc = Rb + m * 16 + lhi * 4 + rg;  // row within tile
      const int rgl = tb + rloc;
      const bool rv = rgl < K_ROWS;
      const float invi = 1.f / fmaxf(sqrtf(norm2[rv ? rgl : K_ROWS - 1]), EPSF);
#pragma unroll
      for (int n = 0; n < 3; ++n) {
        const int cloc = Cb + n * 16 + rowl;        // col within tile
        const float e = __expf(acc[m][n][rg] * invi * invj[n] * INV_T);
        const bool keep = rv && cval[n] && !(diagT && rloc == cloc);
        acc[m][n][rg] = keep ? e : 0.f;
      }
    }
  }
  // row-side sums (rows of ti)
#pragma unroll
  for (int m = 0; m < 3; ++m) {
#pragma unroll
    for (int rg = 0; rg < 4; ++rg) {
      float s = acc[m][0][rg] + acc[m][1][rg] + acc[m][2][rg];
      s += __shfl_xor(s, 1); s += __shfl_xor(s, 2);
      s += __shfl_xor(s, 4); s += __shfl_xor(s, 8);
      if (rowl == 0) {
        const int rgl = tb + Rb + m * 16 + lhi * 4 + rg;
        if (rgl < K_ROWS) atomicAdd(&rowsum[rgl], s);
      }
    }
  }
  // col-side sums (rows of tj) for off-diagonal tiles
  if (!diagT) {
#pragma unroll
    for (int n = 0; n < 3; ++n) {
      float s = 0.f;
#pragma unroll
      for (int m = 0; m < 3; ++m)
#pragma unroll
        for (int rg = 0; rg < 4; ++rg) s += acc[m][n][rg];
      s += __shfl_xor(s, 16); s += __shfl_xor(s, 32);
      if (lhi == 0) {
        const int cg = tjb + Cb + n * 16 + rowl;
        if (cg < K_ROWS) atomicAdd(&rowsum[cg], s);
      }
    }
  }
}

// ---------------------------------------------------------------------------
// K3: lse_i = log(rowsum_i) (diag excluded in gram), pos_i exact fp32 from
// posdot/norm2; neloss = mean of entropy-in-bits. Final scalar.
// ---------------------------------------------------------------------------
__global__ __launch_bounds__(256) void final_kernel(
    const float* __restrict__ rowsum, const float* __restrict__ norm2,
    const float* __restrict__ posdot, const double* __restrict__ entpart,
    float* __restrict__ out) {
  __shared__ double red[4];
  __shared__ double rede[4];
  const int t = threadIdx.x, lane = t & 63, wave = t >> 6;
  double ssum = 0.0;
  for (int i = t; i < K_ROWS; i += 256) {
    const float invi = 1.f / fmaxf(sqrtf(norm2[i]), EPSF);
    const float lse = __logf(rowsum[i]);
    const int ip = (i < N_FEAT) ? i : i - N_FEAT;
    const int io = (i < N_FEAT) ? i + N_FEAT : i - N_FEAT;
    const float invo = 1.f / fmaxf(sqrtf(norm2[io]), EPSF);
    const float pos = posdot[ip] * invi * invo * INV_T;
    ssum += (double)(lse - pos);
  }
  double esum = entpart[t];
#pragma unroll
  for (int off = 1; off < 64; off <<= 1) {
    ssum += __shfl_xor(ssum, off);
    esum += __shfl_xor(esum, off);
  }
  if (lane == 0) { red[wave] = ssum; rede[wave] = esum; }
  __syncthreads();
  if (t == 0) {
    const double ce = (red[0] + red[1] + red[2] + red[3]) / (double)K_ROWS;
    const double etot = rede[0] + rede[1] + rede[2] + rede[3];
    const double nel = etot / ((double)K_ROWS * (double)B_DIM);  // already bits
    out[0] = (float)(ce - nel);
  }
}

extern "C" void kernel_launch(void* const* d_in, const int* in_sizes, int n_in,
                              void* d_out, int out_size, void* d_ws, size_t ws_size,
                              hipStream_t stream) {
  const float* f1 = (const float*)d_in[0];
  const float* f2 = (const float*)d_in[1];
  char* ws = (char*)d_ws;
  unsigned short* fT = (unsigned short*)(ws + FT_OFF);
  float* norm2 = (float*)(ws + NORM2_OFF);
  float* rowsum = (float*)(ws + RSUM_OFF);
  float* posdot = (float*)(ws + PDOT_OFF);
  double* entpart = (double*)(ws + ENT_OFF);

  // zero all accumulators (ws is poisoned 0xAA before every call)
  hipMemsetAsync(ws + NORM2_OFF, 0, (size_t)(WS_END - NORM2_OFF), stream);

  prep_kernel<<<dim3(B_DIM / 64, N_FEAT / 64), 256, 0, stream>>>(f1, f2, fT, norm2, posdot, entpart);
  gram_kernel<<<NTILES, 256, 0, stream>>>(fT, norm2, rowsum);
  final_kernel<<<1, 256, 0, stream>>>(rowsum, norm2, posdot, entpart, (float*)d_out);
}